// Round 2
// baseline (335.508 us; speedup 1.0000x reference)
//
#include <hip/hip_runtime.h>

typedef __attribute__((ext_vector_type(8))) short bf16x8;
typedef __attribute__((ext_vector_type(8))) unsigned short u16x8;
typedef __attribute__((ext_vector_type(4))) unsigned short u16x4;
typedef __attribute__((ext_vector_type(4))) float f32x4;

constexpr int BH  = 64;    // B*H
constexpr int SEQ = 4096;  // N
constexpr int DIM = 64;    // D
constexpr int PM  = 256;   // M (proj_len)
constexpr size_t PLANE = (size_t)BH * PM * DIM;   // 1,048,576 elements

__device__ __forceinline__ unsigned short f2bf(float f){
    unsigned int u = __float_as_uint(f);
    return (unsigned short)((u + 0x7fffu + ((u >> 16) & 1u)) >> 16);
}
__device__ __forceinline__ float bf2f(unsigned short h){
    return __uint_as_float(((unsigned int)h) << 16);
}

// ---------------- kernel 1: E [N][M] f32 -> Et_hi/Et_lo [M][N] bf16 (split) ----------------
__global__ __launch_bounds__(256) void prep_e_kernel(const float* __restrict__ E,
                                                     unsigned short* __restrict__ Et_hi,
                                                     unsigned short* __restrict__ Et_lo){
    __shared__ float T[64][65];
    int n0 = (blockIdx.x & 63) * 64;
    int m0 = (blockIdx.x >> 6) * 64;
    int t = threadIdx.x;
    #pragma unroll
    for (int i = 0; i < 16; ++i){
        int idx = t + i * 256;
        int nl = idx >> 6, ml = idx & 63;
        T[nl][ml] = E[(size_t)(n0 + nl) * PM + (m0 + ml)];
    }
    __syncthreads();
    #pragma unroll
    for (int i = 0; i < 16; ++i){
        int idx = t + i * 256;
        int ml = idx >> 6, nl = idx & 63;
        float v = T[nl][ml];
        unsigned short h = f2bf(v);
        unsigned short lo = f2bf(v - bf2f(h));
        size_t o = (size_t)(m0 + ml) * SEQ + (n0 + nl);
        Et_hi[o] = h;
        Et_lo[o] = lo;
    }
}

// ---------------- kernel 2: projections (split-K over n when NS>1) ----------------
// NS>1: writes f32 partials  PK[s][bh][m][d], PV[s][bh][d][m]
// NS=1: writes final Kp_hi/Kp_lo [bh][m][d] and Vpt [bh][d][m] directly
template<int NS>
__global__ __launch_bounds__(256) void proj_kernel(const float* __restrict__ K,
                                                   const float* __restrict__ V,
                                                   const unsigned short* __restrict__ Et_hi,
                                                   const unsigned short* __restrict__ Et_lo,
                                                   unsigned short* __restrict__ Kp_hi,
                                                   unsigned short* __restrict__ Kp_lo,
                                                   unsigned short* __restrict__ Vpt,
                                                   float* __restrict__ PK,
                                                   float* __restrict__ PV){
    __shared__ unsigned short Eh[64][72], El[64][72], Kh[64][72], Kl[64][72], Vh[64][72];
    int bid     = blockIdx.x;
    int per_xcd = (BH * 4 * NS) / 8;
    int orig    = (bid & 7) * per_xcd + (bid >> 3);   // XCD-chunked
    int bh      = orig / (4 * NS);
    int rem     = orig % (4 * NS);
    int m0      = (rem & 3) * 64;    // m fastest: same-s blocks co-scheduled share K/V range
    int s       = rem >> 2;
    int nbase   = s * (SEQ / NS);
    int t = threadIdx.x;
    int w = t >> 6, l = t & 63, l15 = l & 15, lg = l >> 4;

    const float* Kb = K + (size_t)bh * SEQ * DIM;
    const float* Vb = V + (size_t)bh * SEQ * DIM;

    f32x4 accK[4], accV[4];
    #pragma unroll
    for (int i = 0; i < 4; ++i){ accK[i] = (f32x4)0.0f; accV[i] = (f32x4)0.0f; }

    for (int n0 = nbase; n0 < nbase + SEQ / NS; n0 += 64){
        // stage Et hi/lo tile [64 m][64 n] (rows padded to 72)
        #pragma unroll
        for (int r = 0; r < 2; ++r){
            int ml = (t >> 3) + r * 32;
            int sc = t & 7;
            const int4* ph = reinterpret_cast<const int4*>(Et_hi + (size_t)(m0 + ml) * SEQ + n0 + sc * 8);
            const int4* pl = reinterpret_cast<const int4*>(Et_lo + (size_t)(m0 + ml) * SEQ + n0 + sc * 8);
            *reinterpret_cast<int4*>(&Eh[ml][sc * 8]) = *ph;
            *reinterpret_cast<int4*>(&El[ml][sc * 8]) = *pl;
        }
        // stage K/V transposed + split: [d][n]
        {
            int d  = t & 63;
            int ng = t >> 6;
            #pragma unroll
            for (int p = 0; p < 2; ++p){
                int nb = p * 32 + ng * 8;
                u16x8 kh, kl, vh;
                #pragma unroll
                for (int i = 0; i < 8; ++i){
                    float kv = Kb[(size_t)(n0 + nb + i) * DIM + d];
                    unsigned short h = f2bf(kv);
                    kh[i] = (short)h;
                    kl[i] = (short)f2bf(kv - bf2f(h));
                    float vv = Vb[(size_t)(n0 + nb + i) * DIM + d];
                    vh[i] = (short)f2bf(vv);
                }
                *reinterpret_cast<u16x8*>(&Kh[d][nb]) = kh;
                *reinterpret_cast<u16x8*>(&Kl[d][nb]) = kl;
                *reinterpret_cast<u16x8*>(&Vh[d][nb]) = vh;
            }
        }
        __syncthreads();
        #pragma unroll
        for (int nk = 0; nk < 2; ++nk){
            int kb = nk * 32 + lg * 8;
            bf16x8 eh[4], el[4];
            #pragma unroll
            for (int ms = 0; ms < 4; ++ms){
                eh[ms] = *reinterpret_cast<const bf16x8*>(&Eh[ms * 16 + l15][kb]);
                el[ms] = *reinterpret_cast<const bf16x8*>(&El[ms * 16 + l15][kb]);
            }
            bf16x8 kh = *reinterpret_cast<const bf16x8*>(&Kh[w * 16 + l15][kb]);
            bf16x8 kl = *reinterpret_cast<const bf16x8*>(&Kl[w * 16 + l15][kb]);
            bf16x8 vh = *reinterpret_cast<const bf16x8*>(&Vh[w * 16 + l15][kb]);
            #pragma unroll
            for (int ms = 0; ms < 4; ++ms){
                accK[ms] = __builtin_amdgcn_mfma_f32_16x16x32_bf16(eh[ms], kh, accK[ms], 0, 0, 0);
                accK[ms] = __builtin_amdgcn_mfma_f32_16x16x32_bf16(eh[ms], kl, accK[ms], 0, 0, 0);
                accK[ms] = __builtin_amdgcn_mfma_f32_16x16x32_bf16(el[ms], kh, accK[ms], 0, 0, 0);
                accV[ms] = __builtin_amdgcn_mfma_f32_16x16x32_bf16(vh, eh[ms], accV[ms], 0, 0, 0);
            }
        }
        __syncthreads();
    }

    #pragma unroll
    for (int ms = 0; ms < 4; ++ms){
        #pragma unroll
        for (int j = 0; j < 4; ++j){
            float kv = accK[ms][j];
            int mg = m0 + ms * 16 + lg * 4 + j;
            int dg = w * 16 + l15;
            float vv = accV[ms][j];
            int dr = w * 16 + lg * 4 + j;
            int mc = m0 + ms * 16 + l15;
            if (NS == 1){
                unsigned short h = f2bf(kv);
                size_t o = ((size_t)bh * PM + mg) * DIM + dg;
                Kp_hi[o] = h;
                Kp_lo[o] = f2bf(kv - bf2f(h));
                Vpt[((size_t)bh * DIM + dr) * PM + mc] = f2bf(vv);
            } else {
                PK[((size_t)s * BH + bh) * PM * DIM + (size_t)mg * DIM + dg] = kv;
                PV[((size_t)s * BH + bh) * DIM * PM + (size_t)dr * PM + mc] = vv;
            }
        }
    }
}

// ---------------- kernel 2b: reduce partials -> Kp_hi/Kp_lo/Vpt ----------------
template<int NS>
__global__ __launch_bounds__(256) void reduce_kernel(const float* __restrict__ PK,
                                                     const float* __restrict__ PV,
                                                     unsigned short* __restrict__ Kp_hi,
                                                     unsigned short* __restrict__ Kp_lo,
                                                     unsigned short* __restrict__ Vpt){
    size_t e4 = (size_t)blockIdx.x * 256 + threadIdx.x;   // one float4 per thread
    const float4* PK4 = reinterpret_cast<const float4*>(PK);
    const float4* PV4 = reinterpret_cast<const float4*>(PV);
    size_t stride4 = PLANE / 4;

    float4 k = PK4[e4];
    float4 v = PV4[e4];
    #pragma unroll
    for (int s = 1; s < NS; ++s){
        float4 a = PK4[e4 + (size_t)s * stride4];
        float4 b = PV4[e4 + (size_t)s * stride4];
        k.x += a.x; k.y += a.y; k.z += a.z; k.w += a.w;
        v.x += b.x; v.y += b.y; v.z += b.z; v.w += b.w;
    }
    float kk[4] = {k.x, k.y, k.z, k.w};
    float vv[4] = {v.x, v.y, v.z, v.w};
    u16x4 hi, lo, vb;
    #pragma unroll
    for (int i = 0; i < 4; ++i){
        unsigned short h = f2bf(kk[i]);
        hi[i] = h;
        lo[i] = f2bf(kk[i] - bf2f(h));
        vb[i] = f2bf(vv[i]);
    }
    *reinterpret_cast<u16x4*>(Kp_hi + e4 * 4) = hi;
    *reinterpret_cast<u16x4*>(Kp_lo + e4 * 4) = lo;
    *reinterpret_cast<u16x4*>(Vpt   + e4 * 4) = vb;
}

// ---------------- kernel 3: attention ----------------
__global__ __launch_bounds__(256) void attn_kernel(const float* __restrict__ Q,
                                                   const unsigned short* __restrict__ Kp_hi,
                                                   const unsigned short* __restrict__ Kp_lo,
                                                   const unsigned short* __restrict__ Vpt,
                                                   float* __restrict__ Out){
    __shared__ unsigned short SQh[64][72], SQl[64][72];
    __shared__ unsigned short SB[2 * 128 * 72];  // Kp staging; later reused as P[64][264]
    unsigned short (*SBh)[72] = reinterpret_cast<unsigned short (*)[72]>(SB);
    unsigned short (*SBl)[72] = reinterpret_cast<unsigned short (*)[72]>(SB + 128 * 72);
    unsigned short (*P)[264]  = reinterpret_cast<unsigned short (*)[264]>(SB);

    int bid  = blockIdx.x;
    int orig = (bid & 7) * 512 + (bid >> 3);  // XCD-chunked: same-head blocks on same XCD
    int bh   = orig >> 6;
    int q0   = (orig & 63) * 64;
    int t = threadIdx.x;
    int w = t >> 6, l = t & 63, l15 = l & 15, lg = l >> 4;

    // stage Q*(1/8) split hi/lo  [64 q][64 d]
    #pragma unroll
    for (int r = 0; r < 2; ++r){
        int q = (t >> 3) + r * 32;
        int s = t & 7;
        const float* src = Q + ((size_t)bh * SEQ + q0 + q) * DIM + s * 8;
        float4 a = *reinterpret_cast<const float4*>(src);
        float4 b = *reinterpret_cast<const float4*>(src + 4);
        float vals[8] = {a.x, a.y, a.z, a.w, b.x, b.y, b.z, b.w};
        u16x8 hi, lo;
        #pragma unroll
        for (int i = 0; i < 8; ++i){
            float v = vals[i] * 0.125f;   // exact scale, fold 1/sqrt(D)
            unsigned short h = f2bf(v);
            hi[i] = h;
            lo[i] = f2bf(v - bf2f(h));
        }
        *reinterpret_cast<u16x8*>(&SQh[q][s * 8]) = hi;
        *reinterpret_cast<u16x8*>(&SQl[q][s * 8]) = lo;
    }

    f32x4 sa[16];
    #pragma unroll
    for (int i = 0; i < 16; ++i) sa[i] = (f32x4)0.0f;
    bf16x8 qh[2], ql[2];

    #pragma unroll
    for (int mh = 0; mh < 2; ++mh){
        // stage Kp half [128 m][64 d] hi/lo
        {
            int ml = t >> 1;
            int hf = t & 1;
            const unsigned short* sh = Kp_hi + ((size_t)bh * PM + mh * 128 + ml) * DIM + hf * 32;
            const unsigned short* sl = Kp_lo + ((size_t)bh * PM + mh * 128 + ml) * DIM + hf * 32;
            #pragma unroll
            for (int c = 0; c < 4; ++c){
                *reinterpret_cast<int4*>(&SBh[ml][hf * 32 + c * 8]) = *reinterpret_cast<const int4*>(sh + c * 8);
                *reinterpret_cast<int4*>(&SBl[ml][hf * 32 + c * 8]) = *reinterpret_cast<const int4*>(sl + c * 8);
            }
        }
        __syncthreads();
        if (mh == 0){
            #pragma unroll
            for (int nk = 0; nk < 2; ++nk){
                qh[nk] = *reinterpret_cast<const bf16x8*>(&SQh[w * 16 + l15][nk * 32 + lg * 8]);
                ql[nk] = *reinterpret_cast<const bf16x8*>(&SQl[w * 16 + l15][nk * 32 + lg * 8]);
            }
        }
        #pragma unroll
        for (int nk = 0; nk < 2; ++nk){
            #pragma unroll
            for (int mt = 0; mt < 8; ++mt){
                bf16x8 bh_ = *reinterpret_cast<const bf16x8*>(&SBh[mt * 16 + l15][nk * 32 + lg * 8]);
                bf16x8 bl_ = *reinterpret_cast<const bf16x8*>(&SBl[mt * 16 + l15][nk * 32 + lg * 8]);
                int mi = mh * 8 + mt;
                sa[mi] = __builtin_amdgcn_mfma_f32_16x16x32_bf16(qh[nk], bh_, sa[mi], 0, 0, 0);
                sa[mi] = __builtin_amdgcn_mfma_f32_16x16x32_bf16(qh[nk], bl_, sa[mi], 0, 0, 0);
                sa[mi] = __builtin_amdgcn_mfma_f32_16x16x32_bf16(ql[nk], bh_, sa[mi], 0, 0, 0);
            }
        }
        __syncthreads();
    }

    // softmax over m=256: per lane-group row j, cols spread over 16 lanes x 16 regs
    float inv[4];
    #pragma unroll
    for (int j = 0; j < 4; ++j){
        float mx = sa[0][j];
        #pragma unroll
        for (int mi = 1; mi < 16; ++mi) mx = fmaxf(mx, sa[mi][j]);
        #pragma unroll
        for (int o = 1; o < 16; o <<= 1) mx = fmaxf(mx, __shfl_xor(mx, o, 64));
        float sum = 0.0f;
        #pragma unroll
        for (int mi = 0; mi < 16; ++mi){
            float p = __expf(sa[mi][j] - mx);
            sa[mi][j] = p;
            sum += p;
        }
        #pragma unroll
        for (int o = 1; o < 16; o <<= 1) sum += __shfl_xor(sum, o, 64);
        inv[j] = 1.0f / sum;
    }

    // redistribute P through LDS (overlays Kp staging; already synced)
    #pragma unroll
    for (int mi = 0; mi < 16; ++mi){
        #pragma unroll
        for (int j = 0; j < 4; ++j){
            P[w * 16 + lg * 4 + j][mi * 16 + l15] = f2bf(sa[mi][j]);
        }
    }
    __syncthreads();

    // PV: out[q][d] = sum_m P[q][m] * Vpt[d][m]
    f32x4 oacc[4];
    #pragma unroll
    for (int i = 0; i < 4; ++i) oacc[i] = (f32x4)0.0f;
    const unsigned short* Vb = Vpt + (size_t)bh * DIM * PM;
    #pragma unroll
    for (int mk = 0; mk < 8; ++mk){
        bf16x8 ap = *reinterpret_cast<const bf16x8*>(&P[w * 16 + l15][mk * 32 + lg * 8]);
        #pragma unroll
        for (int dt = 0; dt < 4; ++dt){
            bf16x8 bv = *reinterpret_cast<const bf16x8*>(Vb + (size_t)(dt * 16 + l15) * PM + mk * 32 + lg * 8);
            oacc[dt] = __builtin_amdgcn_mfma_f32_16x16x32_bf16(ap, bv, oacc[dt], 0, 0, 0);
        }
    }

    #pragma unroll
    for (int dt = 0; dt < 4; ++dt){
        #pragma unroll
        for (int j = 0; j < 4; ++j){
            int qg = q0 + w * 16 + lg * 4 + j;
            Out[((size_t)bh * SEQ + qg) * DIM + dt * 16 + l15] = oacc[dt][j] * inv[j];
        }
    }
}

extern "C" void kernel_launch(void* const* d_in, const int* in_sizes, int n_in,
                              void* d_out, int out_size, void* d_ws, size_t ws_size,
                              hipStream_t stream){
    const float* Q = (const float*)d_in[0];
    const float* K = (const float*)d_in[1];
    const float* V = (const float*)d_in[2];
    const float* E = (const float*)d_in[3];
    float* out = (float*)d_out;

    unsigned short* Et_hi = (unsigned short*)d_ws;                       // [M][N]
    unsigned short* Et_lo = Et_hi + (size_t)PM * SEQ;                    // [M][N]
    unsigned short* Kp_hi = Et_lo + (size_t)PM * SEQ;                    // [BH][M][D]
    unsigned short* Kp_lo = Kp_hi + PLANE;                               // [BH][M][D]
    unsigned short* Vpt   = Kp_lo + PLANE;                               // [BH][D][M]
    size_t base_bytes = ( (size_t)PM * SEQ * 2 + PLANE * 3 ) * sizeof(unsigned short);
    float* PK = reinterpret_cast<float*>((char*)d_ws + base_bytes);      // [NS][BH][M][D]
    float* PV = PK + 4 * PLANE;                                          // [NS][BH][D][M]
    size_t need = base_bytes + 8 * PLANE * sizeof(float);

    prep_e_kernel<<<256, 256, 0, stream>>>(E, Et_hi, Et_lo);
    if (ws_size >= need){
        proj_kernel<4><<<1024, 256, 0, stream>>>(K, V, Et_hi, Et_lo, Kp_hi, Kp_lo, Vpt, PK, PV);
        reduce_kernel<4><<<PLANE / 4 / 256, 256, 0, stream>>>(PK, PV, Kp_hi, Kp_lo, Vpt);
    } else {
        proj_kernel<1><<<256, 256, 0, stream>>>(K, V, Et_hi, Et_lo, Kp_hi, Kp_lo, Vpt, nullptr, nullptr);
    }
    attn_kernel<<<4096, 256, 0, stream>>>(Q, Kp_hi, Kp_lo, Vpt, out);
}

// Round 3
// 220.974 us; speedup vs baseline: 1.5183x; 1.5183x over previous
//
#include <hip/hip_runtime.h>

typedef __attribute__((ext_vector_type(8))) short bf16x8;
typedef __attribute__((ext_vector_type(8))) unsigned short u16x8;
typedef __attribute__((ext_vector_type(4))) float f32x4;

constexpr int BH  = 64;    // B*H
constexpr int SEQ = 4096;  // N
constexpr int DIM = 64;    // D
constexpr int PM  = 256;   // M (proj_len)
constexpr size_t PLANE = (size_t)BH * PM * DIM;   // 1,048,576 elements

__device__ __forceinline__ unsigned short f2bf(float f){
    unsigned int u = __float_as_uint(f);
    return (unsigned short)((u + 0x7fffu + ((u >> 16) & 1u)) >> 16);
}
__device__ __forceinline__ float bf2f(unsigned short h){
    return __uint_as_float(((unsigned int)h) << 16);
}

// ---------------- kernel 1: E [N][M] f32 -> Et_hi/Et_lo [M][N] bf16 (split) ----------------
__global__ __launch_bounds__(256) void prep_e_kernel(const float* __restrict__ E,
                                                     unsigned short* __restrict__ Et_hi,
                                                     unsigned short* __restrict__ Et_lo){
    __shared__ float T[64][65];
    int n0 = (blockIdx.x & 63) * 64;
    int m0 = (blockIdx.x >> 6) * 64;
    int t = threadIdx.x;
    #pragma unroll
    for (int i = 0; i < 16; ++i){
        int idx = t + i * 256;
        int nl = idx >> 6, ml = idx & 63;
        T[nl][ml] = E[(size_t)(n0 + nl) * PM + (m0 + ml)];
    }
    __syncthreads();
    #pragma unroll
    for (int i = 0; i < 16; ++i){
        int idx = t + i * 256;
        int ml = idx >> 6, nl = idx & 63;
        float v = T[nl][ml];
        unsigned short h = f2bf(v);
        unsigned short lo = f2bf(v - bf2f(h));
        size_t o = (size_t)(m0 + ml) * SEQ + (n0 + nl);
        Et_hi[o] = h;
        Et_lo[o] = lo;
    }
}

// ---------------- kernel 2: projections, K/V read exactly once ----------------
// grid = 512: s = bid&7 (one n-slice of 512 per XCD -> shared Et slice in L2),
// bh = bid>>3. Block covers ALL m=256 (wave w -> m-chunk w*64) x all d=64.
// K_proj[bh][m][d] hi/lo bf16; Vpt[bh][d][m] bf16.
__global__ __launch_bounds__(256, 2) void proj_kernel(const float* __restrict__ K,
                                                      const float* __restrict__ V,
                                                      const unsigned short* __restrict__ Et_hi,
                                                      const unsigned short* __restrict__ Et_lo,
                                                      unsigned short* __restrict__ Kp_hi,
                                                      unsigned short* __restrict__ Kp_lo,
                                                      unsigned short* __restrict__ Vpt){
    __shared__ unsigned short Kh[64][72], Kl[64][72], Vh[64][72];
    int bid   = blockIdx.x;
    int s     = bid & 7;          // default dispatch round-robins XCDs: same-s -> same XCD
    int bh    = bid >> 3;
    int nbase = s * (SEQ / 8);
    int t = threadIdx.x;
    int w = t >> 6, l = t & 63, l15 = l & 15, lg = l >> 4;
    int m0w = w * 64;             // wave's m-chunk

    const float* Kb = K + (size_t)bh * SEQ * DIM;
    const float* Vb = V + (size_t)bh * SEQ * DIM;

    f32x4 accK[4][4];   // [ms][dt]
    f32x4 accV[4][4];   // [dt][ms]
    #pragma unroll
    for (int i = 0; i < 4; ++i)
        #pragma unroll
        for (int j = 0; j < 4; ++j){ accK[i][j] = (f32x4)0.0f; accV[i][j] = (f32x4)0.0f; }

    for (int n0 = nbase; n0 < nbase + SEQ / 8; n0 += 64){
        // (a) E^T fragments straight from global (L2-resident slice, shared per XCD)
        bf16x8 eh[2][4], el[2][4];
        #pragma unroll
        for (int nk = 0; nk < 2; ++nk){
            #pragma unroll
            for (int ms = 0; ms < 4; ++ms){
                size_t off = (size_t)(m0w + ms * 16 + l15) * SEQ + (n0 + nk * 32 + lg * 8);
                eh[nk][ms] = *reinterpret_cast<const bf16x8*>(Et_hi + off);
                el[nk][ms] = *reinterpret_cast<const bf16x8*>(Et_lo + off);
            }
        }
        // (b) stage K/V transposed + split into LDS: [d][n]
        {
            int d  = t & 63;
            int ng = t >> 6;
            #pragma unroll
            for (int p = 0; p < 2; ++p){
                int nb = p * 32 + ng * 8;
                u16x8 kh, kl, vh;
                #pragma unroll
                for (int i = 0; i < 8; ++i){
                    float kv = Kb[(size_t)(n0 + nb + i) * DIM + d];
                    unsigned short h = f2bf(kv);
                    kh[i] = (short)h;
                    kl[i] = (short)f2bf(kv - bf2f(h));
                    float vv = Vb[(size_t)(n0 + nb + i) * DIM + d];
                    vh[i] = (short)f2bf(vv);
                }
                *reinterpret_cast<u16x8*>(&Kh[d][nb]) = kh;
                *reinterpret_cast<u16x8*>(&Kl[d][nb]) = kl;
                *reinterpret_cast<u16x8*>(&Vh[d][nb]) = vh;
            }
        }
        __syncthreads();
        // (c) MFMA: 128 per wave per iter
        #pragma unroll
        for (int nk = 0; nk < 2; ++nk){
            int kb = nk * 32 + lg * 8;
            #pragma unroll
            for (int dt = 0; dt < 4; ++dt){
                bf16x8 kh = *reinterpret_cast<const bf16x8*>(&Kh[dt * 16 + l15][kb]);
                bf16x8 kl = *reinterpret_cast<const bf16x8*>(&Kl[dt * 16 + l15][kb]);
                bf16x8 vh = *reinterpret_cast<const bf16x8*>(&Vh[dt * 16 + l15][kb]);
                #pragma unroll
                for (int ms = 0; ms < 4; ++ms){
                    accK[ms][dt] = __builtin_amdgcn_mfma_f32_16x16x32_bf16(eh[nk][ms], kh, accK[ms][dt], 0, 0, 0);
                    accK[ms][dt] = __builtin_amdgcn_mfma_f32_16x16x32_bf16(eh[nk][ms], kl, accK[ms][dt], 0, 0, 0);
                    accK[ms][dt] = __builtin_amdgcn_mfma_f32_16x16x32_bf16(el[nk][ms], kh, accK[ms][dt], 0, 0, 0);
                    accV[dt][ms] = __builtin_amdgcn_mfma_f32_16x16x32_bf16(vh, eh[nk][ms], accV[dt][ms], 0, 0, 0);
                }
            }
        }
        __syncthreads();
    }

    // epilogue: atomic-free partial sums across the 8 n-slices? No — each (bh,m,d)
    // is owned by exactly one block per s... s splits n, so SUM over s is needed!
    // -> accumulate via global atomics? No: use per-s partial planes? Instead we
    //    exploit: each (bh) has 8 s-blocks; they accumulate into f32 planes with
    //    atomicAdd-free striped ownership is impossible. Use atomicAdd (f32, device
    //    scope, 8 adders per element, deterministic? atomicAdd order varies ->
    //    f32 non-determinism across replays is NOT allowed... so: partials.
    // NOTE: handled instead by PARTIAL planes + reduce (see below).
    #pragma unroll
    for (int ms = 0; ms < 4; ++ms){
        #pragma unroll
        for (int dt = 0; dt < 4; ++dt){
            #pragma unroll
            for (int j = 0; j < 4; ++j){
                // placeholder: overwritten by partial-plane variant below
            }
        }
    }
}

// The kernel above has a flaw (s splits the reduction). Real implementation:
// partial f32 planes [8][bh][...] + reduce. Kept in one kernel via template.
template<int DUMMY>
__global__ __launch_bounds__(256, 2) void proj_partial_kernel(const float* __restrict__ K,
                                                              const float* __restrict__ V,
                                                              const unsigned short* __restrict__ Et_hi,
                                                              const unsigned short* __restrict__ Et_lo,
                                                              float* __restrict__ PK,
                                                              float* __restrict__ PV){
    __shared__ unsigned short Kh[64][72], Kl[64][72], Vh[64][72];
    int bid   = blockIdx.x;
    int s     = bid & 7;
    int bh    = bid >> 3;
    int nbase = s * (SEQ / 8);
    int t = threadIdx.x;
    int w = t >> 6, l = t & 63, l15 = l & 15, lg = l >> 4;
    int m0w = w * 64;

    const float* Kb = K + (size_t)bh * SEQ * DIM;
    const float* Vb = V + (size_t)bh * SEQ * DIM;

    f32x4 accK[4][4], accV[4][4];
    #pragma unroll
    for (int i = 0; i < 4; ++i)
        #pragma unroll
        for (int j = 0; j < 4; ++j){ accK[i][j] = (f32x4)0.0f; accV[i][j] = (f32x4)0.0f; }

    for (int n0 = nbase; n0 < nbase + SEQ / 8; n0 += 64){
        bf16x8 eh[2][4], el[2][4];
        #pragma unroll
        for (int nk = 0; nk < 2; ++nk){
            #pragma unroll
            for (int ms = 0; ms < 4; ++ms){
                size_t off = (size_t)(m0w + ms * 16 + l15) * SEQ + (n0 + nk * 32 + lg * 8);
                eh[nk][ms] = *reinterpret_cast<const bf16x8*>(Et_hi + off);
                el[nk][ms] = *reinterpret_cast<const bf16x8*>(Et_lo + off);
            }
        }
        {
            int d  = t & 63;
            int ng = t >> 6;
            #pragma unroll
            for (int p = 0; p < 2; ++p){
                int nb = p * 32 + ng * 8;
                u16x8 kh, kl, vh;
                #pragma unroll
                for (int i = 0; i < 8; ++i){
                    float kv = Kb[(size_t)(n0 + nb + i) * DIM + d];
                    unsigned short h = f2bf(kv);
                    kh[i] = (short)h;
                    kl[i] = (short)f2bf(kv - bf2f(h));
                    float vv = Vb[(size_t)(n0 + nb + i) * DIM + d];
                    vh[i] = (short)f2bf(vv);
                }
                *reinterpret_cast<u16x8*>(&Kh[d][nb]) = kh;
                *reinterpret_cast<u16x8*>(&Kl[d][nb]) = kl;
                *reinterpret_cast<u16x8*>(&Vh[d][nb]) = vh;
            }
        }
        __syncthreads();
        #pragma unroll
        for (int nk = 0; nk < 2; ++nk){
            int kb = nk * 32 + lg * 8;
            #pragma unroll
            for (int dt = 0; dt < 4; ++dt){
                bf16x8 kh = *reinterpret_cast<const bf16x8*>(&Kh[dt * 16 + l15][kb]);
                bf16x8 kl = *reinterpret_cast<const bf16x8*>(&Kl[dt * 16 + l15][kb]);
                bf16x8 vh = *reinterpret_cast<const bf16x8*>(&Vh[dt * 16 + l15][kb]);
                #pragma unroll
                for (int ms = 0; ms < 4; ++ms){
                    accK[ms][dt] = __builtin_amdgcn_mfma_f32_16x16x32_bf16(eh[nk][ms], kh, accK[ms][dt], 0, 0, 0);
                    accK[ms][dt] = __builtin_amdgcn_mfma_f32_16x16x32_bf16(eh[nk][ms], kl, accK[ms][dt], 0, 0, 0);
                    accK[ms][dt] = __builtin_amdgcn_mfma_f32_16x16x32_bf16(el[nk][ms], kh, accK[ms][dt], 0, 0, 0);
                    accV[dt][ms] = __builtin_amdgcn_mfma_f32_16x16x32_bf16(vh, eh[nk][ms], accV[dt][ms], 0, 0, 0);
                }
            }
        }
        __syncthreads();
    }

    // partial planes: PK[s][bh][m][d], PV[s][bh][d][m]  (f32)
    float* PKb = PK + ((size_t)s * BH + bh) * PM * DIM;
    float* PVb = PV + ((size_t)s * BH + bh) * DIM * PM;
    #pragma unroll
    for (int ms = 0; ms < 4; ++ms){
        #pragma unroll
        for (int dt = 0; dt < 4; ++dt){
            #pragma unroll
            for (int j = 0; j < 4; ++j){
                int mg = m0w + ms * 16 + lg * 4 + j;
                int dg = dt * 16 + l15;
                PKb[(size_t)mg * DIM + dg] = accK[ms][dt][j];
                int dr = dt * 16 + lg * 4 + j;
                int mc = m0w + ms * 16 + l15;
                PVb[(size_t)dr * PM + mc] = accV[dt][ms][j];
            }
        }
    }
}

// ---------------- kernel 2b: reduce 8 partials -> Kp_hi/Kp_lo/Vpt ----------------
__global__ __launch_bounds__(256) void reduce_kernel(const float* __restrict__ PK,
                                                     const float* __restrict__ PV,
                                                     unsigned short* __restrict__ Kp_hi,
                                                     unsigned short* __restrict__ Kp_lo,
                                                     unsigned short* __restrict__ Vpt){
    size_t e4 = (size_t)blockIdx.x * 256 + threadIdx.x;   // one float4 per thread
    const float4* PK4 = reinterpret_cast<const float4*>(PK);
    const float4* PV4 = reinterpret_cast<const float4*>(PV);
    size_t stride4 = PLANE / 4;

    float4 k = PK4[e4];
    float4 v = PV4[e4];
    #pragma unroll
    for (int s = 1; s < 8; ++s){
        float4 a = PK4[e4 + (size_t)s * stride4];
        float4 b = PV4[e4 + (size_t)s * stride4];
        k.x += a.x; k.y += a.y; k.z += a.z; k.w += a.w;
        v.x += b.x; v.y += b.y; v.z += b.z; v.w += b.w;
    }
    float kk[4] = {k.x, k.y, k.z, k.w};
    float vv[4] = {v.x, v.y, v.z, v.w};
    typedef __attribute__((ext_vector_type(4))) unsigned short u16x4;
    u16x4 hi, lo, vb;
    #pragma unroll
    for (int i = 0; i < 4; ++i){
        unsigned short h = f2bf(kk[i]);
        hi[i] = h;
        lo[i] = f2bf(kk[i] - bf2f(h));
        vb[i] = f2bf(vv[i]);
    }
    *reinterpret_cast<u16x4*>(Kp_hi + e4 * 4) = hi;
    *reinterpret_cast<u16x4*>(Kp_lo + e4 * 4) = lo;
    *reinterpret_cast<u16x4*>(Vpt   + e4 * 4) = vb;
}

// ---------------- kernel 3: attention (unchanged) ----------------
__global__ __launch_bounds__(256) void attn_kernel(const float* __restrict__ Q,
                                                   const unsigned short* __restrict__ Kp_hi,
                                                   const unsigned short* __restrict__ Kp_lo,
                                                   const unsigned short* __restrict__ Vpt,
                                                   float* __restrict__ Out){
    __shared__ unsigned short SQh[64][72], SQl[64][72];
    __shared__ unsigned short SB[2 * 128 * 72];  // Kp staging; later reused as P[64][264]
    unsigned short (*SBh)[72] = reinterpret_cast<unsigned short (*)[72]>(SB);
    unsigned short (*SBl)[72] = reinterpret_cast<unsigned short (*)[72]>(SB + 128 * 72);
    unsigned short (*P)[264]  = reinterpret_cast<unsigned short (*)[264]>(SB);

    int bid  = blockIdx.x;
    int orig = (bid & 7) * 512 + (bid >> 3);  // XCD-chunked: same-head blocks on same XCD
    int bh   = orig >> 6;
    int q0   = (orig & 63) * 64;
    int t = threadIdx.x;
    int w = t >> 6, l = t & 63, l15 = l & 15, lg = l >> 4;

    #pragma unroll
    for (int r = 0; r < 2; ++r){
        int q = (t >> 3) + r * 32;
        int s = t & 7;
        const float* src = Q + ((size_t)bh * SEQ + q0 + q) * DIM + s * 8;
        float4 a = *reinterpret_cast<const float4*>(src);
        float4 b = *reinterpret_cast<const float4*>(src + 4);
        float vals[8] = {a.x, a.y, a.z, a.w, b.x, b.y, b.z, b.w};
        u16x8 hi, lo;
        #pragma unroll
        for (int i = 0; i < 8; ++i){
            float v = vals[i] * 0.125f;
            unsigned short h = f2bf(v);
            hi[i] = h;
            lo[i] = f2bf(v - bf2f(h));
        }
        *reinterpret_cast<u16x8*>(&SQh[q][s * 8]) = hi;
        *reinterpret_cast<u16x8*>(&SQl[q][s * 8]) = lo;
    }

    f32x4 sa[16];
    #pragma unroll
    for (int i = 0; i < 16; ++i) sa[i] = (f32x4)0.0f;
    bf16x8 qh[2], ql[2];

    #pragma unroll
    for (int mh = 0; mh < 2; ++mh){
        {
            int ml = t >> 1;
            int hf = t & 1;
            const unsigned short* sh = Kp_hi + ((size_t)bh * PM + mh * 128 + ml) * DIM + hf * 32;
            const unsigned short* sl = Kp_lo + ((size_t)bh * PM + mh * 128 + ml) * DIM + hf * 32;
            #pragma unroll
            for (int c = 0; c < 4; ++c){
                *reinterpret_cast<int4*>(&SBh[ml][hf * 32 + c * 8]) = *reinterpret_cast<const int4*>(sh + c * 8);
                *reinterpret_cast<int4*>(&SBl[ml][hf * 32 + c * 8]) = *reinterpret_cast<const int4*>(sl + c * 8);
            }
        }
        __syncthreads();
        if (mh == 0){
            #pragma unroll
            for (int nk = 0; nk < 2; ++nk){
                qh[nk] = *reinterpret_cast<const bf16x8*>(&SQh[w * 16 + l15][nk * 32 + lg * 8]);
                ql[nk] = *reinterpret_cast<const bf16x8*>(&SQl[w * 16 + l15][nk * 32 + lg * 8]);
            }
        }
        #pragma unroll
        for (int nk = 0; nk < 2; ++nk){
            #pragma unroll
            for (int mt = 0; mt < 8; ++mt){
                bf16x8 bh_ = *reinterpret_cast<const bf16x8*>(&SBh[mt * 16 + l15][nk * 32 + lg * 8]);
                bf16x8 bl_ = *reinterpret_cast<const bf16x8*>(&SBl[mt * 16 + l15][nk * 32 + lg * 8]);
                int mi = mh * 8 + mt;
                sa[mi] = __builtin_amdgcn_mfma_f32_16x16x32_bf16(qh[nk], bh_, sa[mi], 0, 0, 0);
                sa[mi] = __builtin_amdgcn_mfma_f32_16x16x32_bf16(qh[nk], bl_, sa[mi], 0, 0, 0);
                sa[mi] = __builtin_amdgcn_mfma_f32_16x16x32_bf16(ql[nk], bh_, sa[mi], 0, 0, 0);
            }
        }
        __syncthreads();
    }

    float inv[4];
    #pragma unroll
    for (int j = 0; j < 4; ++j){
        float mx = sa[0][j];
        #pragma unroll
        for (int mi = 1; mi < 16; ++mi) mx = fmaxf(mx, sa[mi][j]);
        #pragma unroll
        for (int o = 1; o < 16; o <<= 1) mx = fmaxf(mx, __shfl_xor(mx, o, 64));
        float sum = 0.0f;
        #pragma unroll
        for (int mi = 0; mi < 16; ++mi){
            float p = __expf(sa[mi][j] - mx);
            sa[mi][j] = p;
            sum += p;
        }
        #pragma unroll
        for (int o = 1; o < 16; o <<= 1) sum += __shfl_xor(sum, o, 64);
        inv[j] = 1.0f / sum;
    }

    #pragma unroll
    for (int mi = 0; mi < 16; ++mi){
        #pragma unroll
        for (int j = 0; j < 4; ++j){
            P[w * 16 + lg * 4 + j][mi * 16 + l15] = f2bf(sa[mi][j]);
        }
    }
    __syncthreads();

    f32x4 oacc[4];
    #pragma unroll
    for (int i = 0; i < 4; ++i) oacc[i] = (f32x4)0.0f;
    const unsigned short* Vb = Vpt + (size_t)bh * DIM * PM;
    #pragma unroll
    for (int mk = 0; mk < 8; ++mk){
        bf16x8 ap = *reinterpret_cast<const bf16x8*>(&P[w * 16 + l15][mk * 32 + lg * 8]);
        #pragma unroll
        for (int dt = 0; dt < 4; ++dt){
            bf16x8 bv = *reinterpret_cast<const bf16x8*>(Vb + (size_t)(dt * 16 + l15) * PM + mk * 32 + lg * 8);
            oacc[dt] = __builtin_amdgcn_mfma_f32_16x16x32_bf16(ap, bv, oacc[dt], 0, 0, 0);
        }
    }

    #pragma unroll
    for (int dt = 0; dt < 4; ++dt){
        #pragma unroll
        for (int j = 0; j < 4; ++j){
            int qg = q0 + w * 16 + lg * 4 + j;
            Out[((size_t)bh * SEQ + qg) * DIM + dt * 16 + l15] = oacc[dt][j] * inv[j];
        }
    }
}

extern "C" void kernel_launch(void* const* d_in, const int* in_sizes, int n_in,
                              void* d_out, int out_size, void* d_ws, size_t ws_size,
                              hipStream_t stream){
    const float* Q = (const float*)d_in[0];
    const float* K = (const float*)d_in[1];
    const float* V = (const float*)d_in[2];
    const float* E = (const float*)d_in[3];
    float* out = (float*)d_out;

    unsigned short* Et_hi = (unsigned short*)d_ws;                       // [M][N]
    unsigned short* Et_lo = Et_hi + (size_t)PM * SEQ;                    // [M][N]
    unsigned short* Kp_hi = Et_lo + (size_t)PM * SEQ;                    // [BH][M][D]
    unsigned short* Kp_lo = Kp_hi + PLANE;                               // [BH][M][D]
    unsigned short* Vpt   = Kp_lo + PLANE;                               // [BH][D][M]
    size_t base_bytes = ((size_t)PM * SEQ * 2 + PLANE * 3) * sizeof(unsigned short);
    float* PK = reinterpret_cast<float*>((char*)d_ws + base_bytes);      // [8][BH][M][D]
    float* PV = PK + 8 * PLANE;                                          // [8][BH][D][M]

    prep_e_kernel<<<256, 256, 0, stream>>>(E, Et_hi, Et_lo);
    proj_partial_kernel<0><<<512, 256, 0, stream>>>(K, V, Et_hi, Et_lo, PK, PV);
    reduce_kernel<<<PLANE / 4 / 256, 256, 0, stream>>>(PK, PV, Kp_hi, Kp_lo, Vpt);
    attn_kernel<<<4096, 256, 0, stream>>>(Q, Kp_hi, Kp_lo, Vpt, out);
}